// Round 2
// baseline (323.246 us; speedup 1.0000x reference)
//
#include <hip/hip_runtime.h>
#include <hip/hip_bf16.h>
#include <type_traits>

// Problem constants: B=4, S=1024, D=2048, H=16, G=2, HD=128
typedef __attribute__((ext_vector_type(8))) __bf16 bf16x8;
typedef __attribute__((ext_vector_type(4))) float floatx4;

__device__ inline floatx4 mfma_bf16(bf16x8 a, bf16x8 b, floatx4 c) {
    return __builtin_amdgcn_mfma_f32_16x16x32_bf16(a, b, c, 0, 0, 0);
}

__device__ inline void g2l16(const __hip_bfloat16* g, __hip_bfloat16* l) {
    __builtin_amdgcn_global_load_lds(
        (const __attribute__((address_space(1))) void*)g,
        (__attribute__((address_space(3))) void*)l, 16, 0, 0);
}

// ---------------- cast f32 -> bf16 (vectorized) ----------------
__global__ void cast_f32_bf16_k(const float* __restrict__ in,
                                __hip_bfloat16* __restrict__ out, int n4) {
    int i = blockIdx.x * blockDim.x + threadIdx.x;
    if (i < n4) {
        float4 v = ((const float4*)in)[i];
        ushort4 u;
        __hip_bfloat16 a0 = __float2bfloat16(v.x), a1 = __float2bfloat16(v.y);
        __hip_bfloat16 a2 = __float2bfloat16(v.z), a3 = __float2bfloat16(v.w);
        u.x = *(unsigned short*)&a0; u.y = *(unsigned short*)&a1;
        u.z = *(unsigned short*)&a2; u.w = *(unsigned short*)&a3;
        ((ushort4*)out)[i] = u;
    }
}

// ---------------- fused prep: all weight transposes + bias concat ----------------
__global__ void prep_k(const float* __restrict__ wq, const float* __restrict__ wk,
                       const float* __restrict__ wv, const float* __restrict__ wo,
                       const float* __restrict__ bq, const float* __restrict__ bk,
                       const float* __restrict__ bv,
                       __hip_bfloat16* __restrict__ wqkvt,
                       __hip_bfloat16* __restrict__ wot,
                       float* __restrict__ bqkv) {
    int bid = blockIdx.x;
    if (bid >= 9216) {
        int i = (bid - 9216) * 256 + threadIdx.x;
        if (i < 2560)
            bqkv[i] = (i < 2048) ? bq[i] : (i < 2304 ? bk[i - 2048] : bv[i - 2304]);
        return;
    }
    const float* W; __hip_bfloat16* Wt; int C, row_off, cb, rb;
    if (bid < 4096)      { W = wq; Wt = wqkvt; C = 2048; row_off = 0;
                           cb = bid & 63; rb = bid >> 6; }
    else if (bid < 4608) { W = wk; Wt = wqkvt; C = 256;  row_off = 2048;
                           int id = bid - 4096; cb = id & 7; rb = id >> 3; }
    else if (bid < 5120) { W = wv; Wt = wqkvt; C = 256;  row_off = 2304;
                           int id = bid - 4608; cb = id & 7; rb = id >> 3; }
    else                 { W = wo; Wt = wot;   C = 2048; row_off = 0;
                           int id = bid - 5120; cb = id & 63; rb = id >> 6; }
    __shared__ float tile[32][33];
    int c0 = cb * 32, r0 = rb * 32;
    int tx = threadIdx.x & 31, ty0 = threadIdx.x >> 5;
#pragma unroll
    for (int i = 0; i < 4; i++) {
        int ty = ty0 + i * 8;
        tile[ty][tx] = W[(size_t)(r0 + ty) * C + c0 + tx];
    }
    __syncthreads();
#pragma unroll
    for (int i = 0; i < 4; i++) {
        int ty = ty0 + i * 8;
        Wt[(size_t)(row_off + c0 + ty) * 2048 + r0 + tx] = __float2bfloat16(tile[tx][ty]);
    }
}

// ---------------- fused QKV GEMM + RoPE epilogue (128x128, 4-slot ring) --------
// A(4096,2048) @ wqkvt(2560,2048)^T. Round-0 verified fragment layout + epilogue.
// K processed as 64 units of 32 in a 4-slot LDS ring (64 KiB total -> 2 blk/CU).
// Phase u: stage unit u+3 (4 x global_load_lds), 10 x ds_read_b128 for unit u,
// s_waitcnt vmcnt(8) (2 units stay in flight - never drains), s_barrier,
// setprio(1), 16 MFMA, setprio(0), s_barrier. Tail peels vmcnt 8->4->0.
// Slot-reuse safety: unit u-1's ds_reads retire before phase u-1's barrier #2
// (compiler lgkmcnt before MFMA); stage of unit u+3 (same slot) issues after it.
__global__ __launch_bounds__(256) void gemm_qkv_k(
    const __hip_bfloat16* __restrict__ A,
    const __hip_bfloat16* __restrict__ Bt,
    const float* __restrict__ bias,
    __hip_bfloat16* __restrict__ Qb,
    __hip_bfloat16* __restrict__ Kb,
    __hip_bfloat16* __restrict__ Vlin) {
    __shared__ alignas(16) __hip_bfloat16 As[4][128 * 32];
    __shared__ alignas(16) __hip_bfloat16 Bs[4][128 * 32];
    const int t = threadIdx.x, lane = t & 63, w = t >> 6;
    const int quad = lane >> 4, l16 = lane & 15;
    const int bm = blockIdx.y, bn = blockIdx.x;
    const int r_ = t >> 2;
    const int kc_ = (t & 3) ^ ((t >> 3) & 3);   // swizzled source chunk
    const int swz = (l16 >> 1) & 3;

    const __hip_bfloat16* gA = A + (size_t)(bm * 128 + r_) * 2048 + kc_ * 8;
    const __hip_bfloat16* gB = Bt + (size_t)(bn * 128 + r_) * 2048 + kc_ * 8;

    floatx4 acc[2][8] = {};

#define STAGE_U(u) do { \
        int sl_ = (u) & 3; \
        g2l16(gA + (u) * 32,             As[sl_] + t * 8); \
        g2l16(gA + (u) * 32 + 64 * 2048, As[sl_] + (t + 256) * 8); \
        g2l16(gB + (u) * 32,             Bs[sl_] + t * 8); \
        g2l16(gB + (u) * 32 + 64 * 2048, Bs[sl_] + (t + 256) * 8); \
    } while (0)

    STAGE_U(0); STAGE_U(1); STAGE_U(2);
    asm volatile("s_waitcnt vmcnt(8)" ::: "memory");   // unit 0 resident
    __builtin_amdgcn_s_barrier();

#define PHASE_U(u, DOSTAGE, VMSTR) do { \
        if (DOSTAGE) STAGE_U((u) + 3); \
        const __hip_bfloat16* pA_ = As[(u) & 3]; \
        const __hip_bfloat16* pB_ = Bs[(u) & 3]; \
        bf16x8 af_[2], bf_[8]; \
        _Pragma("unroll") for (int mi_ = 0; mi_ < 2; ++mi_) \
            af_[mi_] = *(const bf16x8*)(pA_ + (w * 32 + mi_ * 16 + l16) * 32 \
                                        + (quad ^ swz) * 8); \
        _Pragma("unroll") for (int ni_ = 0; ni_ < 8; ++ni_) \
            bf_[ni_] = *(const bf16x8*)(pB_ + (ni_ * 16 + l16) * 32 \
                                        + (quad ^ swz) * 8); \
        asm volatile("s_waitcnt " VMSTR ::: "memory"); /* unit u+1 resident */ \
        __builtin_amdgcn_s_barrier(); \
        __builtin_amdgcn_s_setprio(1); \
        _Pragma("unroll") for (int mi_ = 0; mi_ < 2; ++mi_) \
            _Pragma("unroll") for (int ni_ = 0; ni_ < 8; ++ni_) \
                acc[mi_][ni_] = mfma_bf16(af_[mi_], bf_[ni_], acc[mi_][ni_]); \
        __builtin_amdgcn_s_setprio(0); \
        __builtin_amdgcn_s_barrier(); \
    } while (0)

    for (int u = 0; u < 61; ++u)
        PHASE_U(u, true, "vmcnt(8)");
    PHASE_U(61, false, "vmcnt(4)");
    PHASE_U(62, false, "vmcnt(0)");
    PHASE_U(63, false, "vmcnt(0)");
#undef PHASE_U
#undef STAGE_U

    // -------- epilogue (round-0 verified, verbatim) --------
    const int row_base = bm * 128 + w * 32 + quad * 4;
    if (bn < 18) {
        // Q (bn<16) or K (bn 16/17): RoPE pairs (j, j+64), j = ni*16+l16, ni<4
        const float scale = (bn < 16) ? 0.0078125f : 1.0f;
        __hip_bfloat16* dst = (bn < 16) ? Qb : Kb;
        const int nh = (bn < 16) ? 16 : 2;
        const int hh = (bn < 16) ? bn : (bn - 16);
#pragma unroll
        for (int ni = 0; ni < 4; ni++) {
            int j = ni * 16 + l16;
            float invf = __expf(-(float)j * (9.210340371976184f / 64.f)); // 10000^{-j/64}
            float bj  = bias[bn * 128 + j];
            float bj2 = bias[bn * 128 + j + 64];
#pragma unroll
            for (int mi = 0; mi < 2; mi++)
#pragma unroll
                for (int r = 0; r < 4; r++) {
                    int row = row_base + mi * 16 + r;
                    int b = row >> 10, s = row & 1023;
                    float vj  = acc[mi][ni][r] + bj;
                    float vj2 = acc[mi][ni + 4][r] + bj2;
                    float sn, cs;
                    __sincosf((float)s * invf, &sn, &cs);
                    __hip_bfloat16* op = dst + ((size_t)(b * nh + hh) * 1024 + s) * 128;
                    op[j]      = __float2bfloat16((vj * cs - vj2 * sn) * scale);
                    op[j + 64] = __float2bfloat16((vj2 * cs + vj * sn) * scale);
                }
        }
    } else {
        int g = bn - 18;
#pragma unroll
        for (int ni = 0; ni < 8; ni++) {
            int col = ni * 16 + l16;
            float bv = bias[bn * 128 + col];
#pragma unroll
            for (int mi = 0; mi < 2; mi++)
#pragma unroll
                for (int r = 0; r < 4; r++) {
                    int row = row_base + mi * 16 + r;
                    Vlin[(size_t)row * 256 + g * 128 + col] =
                        __float2bfloat16(acc[mi][ni][r] + bv);
                }
        }
    }
}

// ---------------- GEMM: C(M,N) = A(M,K) @ Bt(N,K)^T + bias (out proj) ----------
// Same 4-slot ring schedule; round-0 fragment layout + epilogue verbatim.
template <typename OUT_T>
__global__ __launch_bounds__(256) void gemm_bt_k(
    const __hip_bfloat16* __restrict__ A,
    const __hip_bfloat16* __restrict__ Bt,
    const float* __restrict__ bias,
    OUT_T* __restrict__ C,
    int M, int N, int K) {
    __shared__ alignas(16) __hip_bfloat16 As[4][128 * 32];
    __shared__ alignas(16) __hip_bfloat16 Bs[4][128 * 32];
    const int t = threadIdx.x;
    const int lane = t & 63;
    const int w = t >> 6;
    const int wm = w & 1, wn = w >> 1;
    const int quad = lane >> 4, l16 = lane & 15;
    const int bm = blockIdx.y, bn = blockIdx.x;
    const int r_ = t >> 2;
    const int kc_ = (t & 3) ^ ((t >> 3) & 3);   // swizzled source chunk
    const int swz = (l16 >> 1) & 3;

    const __hip_bfloat16* gA = A + (size_t)(bm * 128 + r_) * K + kc_ * 8;
    const __hip_bfloat16* gB = Bt + (size_t)(bn * 128 + r_) * K + kc_ * 8;

    floatx4 acc[4][4] = {};

#define STAGE_U(u) do { \
        int sl_ = (u) & 3; \
        g2l16(gA + (size_t)(u) * 32,            As[sl_] + t * 8); \
        g2l16(gA + (size_t)(u) * 32 + 64 * K,   As[sl_] + (t + 256) * 8); \
        g2l16(gB + (size_t)(u) * 32,            Bs[sl_] + t * 8); \
        g2l16(gB + (size_t)(u) * 32 + 64 * K,   Bs[sl_] + (t + 256) * 8); \
    } while (0)

    const int nu = K >> 5;
    STAGE_U(0); STAGE_U(1); STAGE_U(2);
    asm volatile("s_waitcnt vmcnt(8)" ::: "memory");
    __builtin_amdgcn_s_barrier();

#define PHASE_U(u, DOSTAGE, VMSTR) do { \
        if (DOSTAGE) STAGE_U((u) + 3); \
        const __hip_bfloat16* pA_ = As[(u) & 3]; \
        const __hip_bfloat16* pB_ = Bs[(u) & 3]; \
        bf16x8 af_[4], bf_[4]; \
        _Pragma("unroll") for (int mi_ = 0; mi_ < 4; ++mi_) \
            af_[mi_] = *(const bf16x8*)(pA_ + (wm * 64 + mi_ * 16 + l16) * 32 \
                                        + (quad ^ swz) * 8); \
        _Pragma("unroll") for (int ni_ = 0; ni_ < 4; ++ni_) \
            bf_[ni_] = *(const bf16x8*)(pB_ + (wn * 64 + ni_ * 16 + l16) * 32 \
                                        + (quad ^ swz) * 8); \
        asm volatile("s_waitcnt " VMSTR ::: "memory"); \
        __builtin_amdgcn_s_barrier(); \
        __builtin_amdgcn_s_setprio(1); \
        _Pragma("unroll") for (int mi_ = 0; mi_ < 4; ++mi_) \
            _Pragma("unroll") for (int ni_ = 0; ni_ < 4; ++ni_) \
                acc[mi_][ni_] = mfma_bf16(af_[mi_], bf_[ni_], acc[mi_][ni_]); \
        __builtin_amdgcn_s_setprio(0); \
        __builtin_amdgcn_s_barrier(); \
    } while (0)

    for (int u = 0; u < nu - 3; ++u)
        PHASE_U(u, true, "vmcnt(8)");
    PHASE_U(nu - 3, false, "vmcnt(4)");
    PHASE_U(nu - 2, false, "vmcnt(0)");
    PHASE_U(nu - 1, false, "vmcnt(0)");
#undef PHASE_U
#undef STAGE_U

#pragma unroll
    for (int mi = 0; mi < 4; mi++) {
        int row0 = bm * 128 + wm * 64 + mi * 16 + quad * 4;
#pragma unroll
        for (int ni = 0; ni < 4; ni++) {
            int col = bn * 128 + wn * 64 + ni * 16 + l16;
            float bv = bias[col];
#pragma unroll
            for (int r = 0; r < 4; r++) {
                float v = acc[mi][ni][r] + bv;
                if constexpr (std::is_same<OUT_T, float>::value)
                    C[(size_t)(row0 + r) * N + col] = v;
                else
                    C[(size_t)(row0 + r) * N + col] = __float2bfloat16(v);
            }
        }
    }
}

// V part of Vlin (4096 x 256) -> VT (B, G, 128, 1024)
__global__ void transpose_v_k(const __hip_bfloat16* __restrict__ Vlin,
                              __hip_bfloat16* __restrict__ VT) {
    __shared__ __hip_bfloat16 tile[32][33];
    int bg = blockIdx.z;
    int b = bg >> 1, g = bg & 1;
    int s0 = blockIdx.y * 32, d0 = blockIdx.x * 32;
    int tx = threadIdx.x & 31, ty0 = threadIdx.x >> 5;
#pragma unroll
    for (int i = 0; i < 4; i++) {
        int ty = ty0 + i * 8;
        tile[ty][tx] = Vlin[(size_t)(b * 1024 + s0 + ty) * 256 + g * 128 + d0 + tx];
    }
    __syncthreads();
#pragma unroll
    for (int i = 0; i < 4; i++) {
        int ty = ty0 + i * 8;
        VT[((size_t)(b * 2 + g) * 128 + d0 + ty) * 1024 + s0 + tx] = tile[tx][ty];
    }
}

// ---------------- flash attention (v4, m97-style staged) ----------------
__global__ __launch_bounds__(256, 2) void attn_k(
    const __hip_bfloat16* __restrict__ Qb,
    const __hip_bfloat16* __restrict__ Kb,
    const __hip_bfloat16* __restrict__ VT,
    __hip_bfloat16* __restrict__ AO) {
    constexpr int PLD = 72;
    __shared__ alignas(16) __hip_bfloat16 Ks[64 * 128];
    __shared__ alignas(16) __hip_bfloat16 Vs[128 * 64];
    __shared__ alignas(16) __hip_bfloat16 Ps[4][32 * PLD];

    const int bh = blockIdx.x;          // b*16 + h
    const int b = bh >> 4, h = bh & 15, g = h >> 3;
    const int t = threadIdx.x, lane = t & 63, w = t >> 6;
    const int quad = lane >> 4, l16 = lane & 15;
    const int q0 = blockIdx.y * 128 + w * 32;

    const __hip_bfloat16* Qp = Qb + ((size_t)bh * 1024 + q0 + l16) * 128 + quad * 8;
    bf16x8 aq[2][4];
#pragma unroll
    for (int mi = 0; mi < 2; mi++)
#pragma unroll
        for (int kc = 0; kc < 4; kc++)
            aq[mi][kc] = *(const bf16x8*)(Qp + mi * 16 * 128 + kc * 32);

    const int bg = b * 2 + g;
    const __hip_bfloat16* Kstage = Kb + (size_t)bg * 1024 * 128
        + (t >> 4) * 128 + ((t & 15) ^ (t >> 4)) * 8;
    const __hip_bfloat16* Vstage = VT + (size_t)bg * 128 * 1024
        + (t >> 3) * 1024 + ((t & 7) ^ ((t >> 3) & 7)) * 8;

    float l_part[2][4] = {};
    floatx4 o[2][8] = {};

    for (int kv = 0; kv < 1024; kv += 64) {
#pragma unroll
        for (int j = 0; j < 4; j++)
            g2l16(Kstage + (size_t)(kv + j * 16) * 128, Ks + (j * 256 + t) * 8);
#pragma unroll
        for (int j = 0; j < 4; j++)
            g2l16(Vstage + (size_t)j * 32 * 1024 + kv, Vs + (j * 256 + t) * 8);
        __syncthreads();

        floatx4 s[2][4] = {};
#pragma unroll
        for (int nj = 0; nj < 4; nj++)
#pragma unroll
            for (int kc = 0; kc < 4; kc++) {
                bf16x8 kb = *(const bf16x8*)(Ks + (nj * 16 + l16) * 128
                                             + (((kc * 4 + quad) ^ l16) * 8));
                s[0][nj] = mfma_bf16(aq[0][kc], kb, s[0][nj]);
                s[1][nj] = mfma_bf16(aq[1][kc], kb, s[1][nj]);
            }

        __hip_bfloat16* pl = Ps[w];
#pragma unroll
        for (int mi = 0; mi < 2; mi++)
#pragma unroll
            for (int nj = 0; nj < 4; nj++)
#pragma unroll
                for (int r = 0; r < 4; r++) {
                    float p = __expf(s[mi][nj][r]);
                    l_part[mi][r] += p;
                    pl[(mi * 16 + quad * 4 + r) * PLD + nj * 16 + l16] =
                        __float2bfloat16(p);
                }
        asm volatile("s_waitcnt lgkmcnt(0)" ::: "memory");

        bf16x8 ap[2][2];
#pragma unroll
        for (int mi = 0; mi < 2; mi++)
#pragma unroll
            for (int kc2 = 0; kc2 < 2; kc2++)
                ap[mi][kc2] = *(const bf16x8*)(pl + (mi * 16 + l16) * PLD
                                               + kc2 * 32 + quad * 8);

#pragma unroll
        for (int ni = 0; ni < 8; ni++)
#pragma unroll
            for (int kc2 = 0; kc2 < 2; kc2++) {
                bf16x8 vb = *(const bf16x8*)(Vs + (ni * 16 + l16) * 64
                                             + (((kc2 * 4 + quad) ^ (l16 & 7)) * 8));
                o[0][ni] = mfma_bf16(ap[0][kc2], vb, o[0][ni]);
                o[1][ni] = mfma_bf16(ap[1][kc2], vb, o[1][ni]);
            }
        __syncthreads();
    }

#pragma unroll
    for (int mi = 0; mi < 2; mi++)
#pragma unroll
        for (int r = 0; r < 4; r++) {
            float sum = l_part[mi][r];
            sum += __shfl_xor(sum, 1);
            sum += __shfl_xor(sum, 2);
            sum += __shfl_xor(sum, 4);
            sum += __shfl_xor(sum, 8);
            float inv = 1.f / sum;
            size_t srow = (size_t)b * 1024 + q0 + mi * 16 + quad * 4 + r;
#pragma unroll
            for (int ni = 0; ni < 8; ni++)
                AO[srow * 2048 + h * 128 + ni * 16 + l16] =
                    __float2bfloat16(o[mi][ni][r] * inv);
        }
}

extern "C" void kernel_launch(void* const* d_in, const int* in_sizes, int n_in,
                              void* d_out, int out_size, void* d_ws, size_t ws_size,
                              hipStream_t stream) {
    (void)in_sizes; (void)n_in; (void)out_size; (void)ws_size;
    const float* x  = (const float*)d_in[0];
    const float* wq = (const float*)d_in[1];
    const float* bq = (const float*)d_in[2];
    const float* wk = (const float*)d_in[3];
    const float* bk = (const float*)d_in[4];
    const float* wv = (const float*)d_in[5];
    const float* bv = (const float*)d_in[6];
    const float* wo = (const float*)d_in[7];
    const float* bo = (const float*)d_in[8];
    float* out = (float*)d_out;

    char* ws = (char*)d_ws;
    __hip_bfloat16* xb    = (__hip_bfloat16*)(ws + 0);          // 16.8 MB (4096x2048)
    __hip_bfloat16* AO    = xb;                                  // alias (xb dead after QKV gemm)
    __hip_bfloat16* wqkvt = (__hip_bfloat16*)(ws + 16777216);   // 10.5 MB (2560x2048)
    __hip_bfloat16* wot   = (__hip_bfloat16*)(ws + 27262976);   // 8.4 MB  (2048x2048)
    __hip_bfloat16* Qb    = (__hip_bfloat16*)(ws + 35651584);   // 16.8 MB (B*H,S,128)
    __hip_bfloat16* Kb    = (__hip_bfloat16*)(ws + 52428800);   // 2.1 MB  (B*G,S,128)
    __hip_bfloat16* Vlin  = (__hip_bfloat16*)(ws + 54525952);   // 2.1 MB  (4096x256)
    __hip_bfloat16* VT    = (__hip_bfloat16*)(ws + 56623104);   // 2.1 MB  (B*G,128,S)
    float*          bqkv  = (float*)(ws + 58720256);            // 10 KB   (2560)

    cast_f32_bf16_k<<<8192, 256, 0, stream>>>(x, xb, 2097152);
    prep_k<<<9226, 256, 0, stream>>>(wq, wk, wv, wo, bq, bk, bv, wqkvt, wot, bqkv);
    gemm_qkv_k<<<dim3(20, 32), 256, 0, stream>>>(xb, wqkvt, bqkv, Qb, Kb, Vlin);
    transpose_v_k<<<dim3(4, 32, 8), 256, 0, stream>>>(Vlin, VT);
    attn_k<<<dim3(64, 8), 256, 0, stream>>>(Qb, Kb, VT, AO);
    gemm_bt_k<float><<<dim3(16, 32), 256, 0, stream>>>(AO, wot, bo, out, 4096, 2048, 2048);
}

// Round 3
// 322.780 us; speedup vs baseline: 1.0014x; 1.0014x over previous
//
#include <hip/hip_runtime.h>
#include <hip/hip_bf16.h>
#include <type_traits>

// Problem constants: B=4, S=1024, D=2048, H=16, G=2, HD=128
typedef __attribute__((ext_vector_type(8))) __bf16 bf16x8;
typedef __attribute__((ext_vector_type(4))) float floatx4;

__device__ inline floatx4 mfma_bf16(bf16x8 a, bf16x8 b, floatx4 c) {
    return __builtin_amdgcn_mfma_f32_16x16x32_bf16(a, b, c, 0, 0, 0);
}

__device__ inline void g2l16(const __hip_bfloat16* g, __hip_bfloat16* l) {
    __builtin_amdgcn_global_load_lds(
        (const __attribute__((address_space(1))) void*)g,
        (__attribute__((address_space(3))) void*)l, 16, 0, 0);
}

// ---------------- cast f32 -> bf16 (vectorized) ----------------
__global__ void cast_f32_bf16_k(const float* __restrict__ in,
                                __hip_bfloat16* __restrict__ out, int n4) {
    int i = blockIdx.x * blockDim.x + threadIdx.x;
    if (i < n4) {
        float4 v = ((const float4*)in)[i];
        ushort4 u;
        __hip_bfloat16 a0 = __float2bfloat16(v.x), a1 = __float2bfloat16(v.y);
        __hip_bfloat16 a2 = __float2bfloat16(v.z), a3 = __float2bfloat16(v.w);
        u.x = *(unsigned short*)&a0; u.y = *(unsigned short*)&a1;
        u.z = *(unsigned short*)&a2; u.w = *(unsigned short*)&a3;
        ((ushort4*)out)[i] = u;
    }
}

// ---------------- fused prep: all weight transposes + bias concat ----------------
__global__ void prep_k(const float* __restrict__ wq, const float* __restrict__ wk,
                       const float* __restrict__ wv, const float* __restrict__ wo,
                       const float* __restrict__ bq, const float* __restrict__ bk,
                       const float* __restrict__ bv,
                       __hip_bfloat16* __restrict__ wqkvt,
                       __hip_bfloat16* __restrict__ wot,
                       float* __restrict__ bqkv) {
    int bid = blockIdx.x;
    if (bid >= 9216) {
        int i = (bid - 9216) * 256 + threadIdx.x;
        if (i < 2560)
            bqkv[i] = (i < 2048) ? bq[i] : (i < 2304 ? bk[i - 2048] : bv[i - 2304]);
        return;
    }
    const float* W; __hip_bfloat16* Wt; int C, row_off, cb, rb;
    if (bid < 4096)      { W = wq; Wt = wqkvt; C = 2048; row_off = 0;
                           cb = bid & 63; rb = bid >> 6; }
    else if (bid < 4608) { W = wk; Wt = wqkvt; C = 256;  row_off = 2048;
                           int id = bid - 4096; cb = id & 7; rb = id >> 3; }
    else if (bid < 5120) { W = wv; Wt = wqkvt; C = 256;  row_off = 2304;
                           int id = bid - 4608; cb = id & 7; rb = id >> 3; }
    else                 { W = wo; Wt = wot;   C = 2048; row_off = 0;
                           int id = bid - 5120; cb = id & 63; rb = id >> 6; }
    __shared__ float tile[32][33];
    int c0 = cb * 32, r0 = rb * 32;
    int tx = threadIdx.x & 31, ty0 = threadIdx.x >> 5;
#pragma unroll
    for (int i = 0; i < 4; i++) {
        int ty = ty0 + i * 8;
        tile[ty][tx] = W[(size_t)(r0 + ty) * C + c0 + tx];
    }
    __syncthreads();
#pragma unroll
    for (int i = 0; i < 4; i++) {
        int ty = ty0 + i * 8;
        Wt[(size_t)(row_off + c0 + ty) * 2048 + r0 + tx] = __float2bfloat16(tile[tx][ty]);
    }
}

// ---------------- fused QKV GEMM + RoPE epilogue (round-0 proven schedule) -----
// A(4096,2048) @ wqkvt(2560,2048)^T. Wave w owns rows w*32..+31 x all 128 cols.
// bn<16: Q head (RoPE, *1/128) -> Qb; bn 16/17: K group (RoPE) -> Kb;
// bn 18/19: V group -> VT directly (LDS-transposed epilogue, was transpose_v_k).
__global__ __launch_bounds__(256) void gemm_qkv_k(
    const __hip_bfloat16* __restrict__ A,
    const __hip_bfloat16* __restrict__ Bt,
    const float* __restrict__ bias,
    __hip_bfloat16* __restrict__ Qb,
    __hip_bfloat16* __restrict__ Kb,
    __hip_bfloat16* __restrict__ VT) {
    __shared__ alignas(16) __hip_bfloat16 As[128 * 32];
    __shared__ alignas(16) __hip_bfloat16 Bs[128 * 32];
    __shared__ alignas(16) __hip_bfloat16 vtile[128][136];  // V-epilogue transpose
    const int t = threadIdx.x, lane = t & 63, w = t >> 6;
    const int quad = lane >> 4, l16 = lane & 15;
    const int bm = blockIdx.y, bn = blockIdx.x;
    const int r_ = t >> 2;
    const int kc_ = (t & 3) ^ ((t >> 3) & 3);   // swizzled source chunk
    const int swz = (l16 >> 1) & 3;

    const __hip_bfloat16* gA = A + (size_t)(bm * 128 + r_) * 2048 + kc_ * 8;
    const __hip_bfloat16* gB = Bt + (size_t)(bn * 128 + r_) * 2048 + kc_ * 8;

    floatx4 acc[2][8] = {};

    for (int kt = 0; kt < 2048; kt += 32) {
        g2l16(gA + kt, As + t * 8);
        g2l16(gA + kt + 64 * 2048, As + (t + 256) * 8);
        g2l16(gB + kt, Bs + t * 8);
        g2l16(gB + kt + 64 * 2048, Bs + (t + 256) * 8);
        __syncthreads();
        bf16x8 af[2], bfr[8];
#pragma unroll
        for (int mi = 0; mi < 2; mi++)
            af[mi] = *(const bf16x8*)(As + (w * 32 + mi * 16 + l16) * 32 + (quad ^ swz) * 8);
#pragma unroll
        for (int ni = 0; ni < 8; ni++)
            bfr[ni] = *(const bf16x8*)(Bs + (ni * 16 + l16) * 32 + (quad ^ swz) * 8);
#pragma unroll
        for (int mi = 0; mi < 2; mi++)
#pragma unroll
            for (int ni = 0; ni < 8; ni++)
                acc[mi][ni] = mfma_bf16(af[mi], bfr[ni], acc[mi][ni]);
        __syncthreads();
    }

    const int row_base = bm * 128 + w * 32 + quad * 4;
    if (bn < 18) {
        // Q (bn<16) or K (bn 16/17): RoPE pairs (j, j+64), j = ni*16+l16, ni<4
        const float scale = (bn < 16) ? 0.0078125f : 1.0f;
        __hip_bfloat16* dst = (bn < 16) ? Qb : Kb;
        const int nh = (bn < 16) ? 16 : 2;
        const int hh = (bn < 16) ? bn : (bn - 16);
#pragma unroll
        for (int ni = 0; ni < 4; ni++) {
            int j = ni * 16 + l16;
            float invf = __expf(-(float)j * (9.210340371976184f / 64.f)); // 10000^{-j/64}
            float bj  = bias[bn * 128 + j];
            float bj2 = bias[bn * 128 + j + 64];
#pragma unroll
            for (int mi = 0; mi < 2; mi++)
#pragma unroll
                for (int r = 0; r < 4; r++) {
                    int row = row_base + mi * 16 + r;
                    int b = row >> 10, s = row & 1023;
                    float vj  = acc[mi][ni][r] + bj;
                    float vj2 = acc[mi][ni + 4][r] + bj2;
                    float sn, cs;
                    __sincosf((float)s * invf, &sn, &cs);
                    __hip_bfloat16* op = dst + ((size_t)(b * nh + hh) * 1024 + s) * 128;
                    op[j]      = __float2bfloat16((vj * cs - vj2 * sn) * scale);
                    op[j + 64] = __float2bfloat16((vj2 * cs + vj * sn) * scale);
                }
        }
    } else {
        // V block: transpose in LDS, write VT[(b*2+g)*128 + d][s] coalesced.
        const int g = bn - 18;
#pragma unroll
        for (int ni = 0; ni < 8; ni++) {
            int col = ni * 16 + l16;
            float bv = bias[bn * 128 + col];
#pragma unroll
            for (int mi = 0; mi < 2; mi++)
#pragma unroll
                for (int r = 0; r < 4; r++) {
                    int lr = w * 32 + mi * 16 + quad * 4 + r;
                    vtile[col][lr] = __float2bfloat16(acc[mi][ni][r] + bv);
                }
        }
        __syncthreads();
        const int b = bm >> 3, s0 = (bm & 7) * 128;
        const int dd = t >> 4, sc8 = (t & 15) * 8;
#pragma unroll
        for (int pass = 0; pass < 8; pass++) {
            int d = pass * 16 + dd;
            bf16x8 v = *(const bf16x8*)&vtile[d][sc8];
            *(bf16x8*)(VT + ((size_t)((b * 2 + g) * 128 + d)) * 1024 + s0 + sc8) = v;
        }
    }
}

// ---------------- GEMM: C(M,N) = A(M,K) @ Bt(N,K)^T + bias (out proj) ----------
template <typename OUT_T>
__global__ __launch_bounds__(256) void gemm_bt_k(
    const __hip_bfloat16* __restrict__ A,
    const __hip_bfloat16* __restrict__ Bt,
    const float* __restrict__ bias,
    OUT_T* __restrict__ C,
    int M, int N, int K) {
    __shared__ alignas(16) __hip_bfloat16 As[128 * 32];
    __shared__ alignas(16) __hip_bfloat16 Bs[128 * 32];
    const int t = threadIdx.x;
    const int lane = t & 63;
    const int w = t >> 6;
    const int wm = w & 1, wn = w >> 1;
    const int quad = lane >> 4, l16 = lane & 15;
    const int bm = blockIdx.y, bn = blockIdx.x;
    const int r_ = t >> 2;
    const int kc_ = (t & 3) ^ ((t >> 3) & 3);   // swizzled source chunk
    const int swz = (l16 >> 1) & 3;

    const __hip_bfloat16* gA = A + (size_t)(bm * 128 + r_) * K + kc_ * 8;
    const __hip_bfloat16* gB = Bt + (size_t)(bn * 128 + r_) * K + kc_ * 8;

    floatx4 acc[4][4] = {};

    for (int kt = 0; kt < K; kt += 32) {
        g2l16(gA + kt, As + t * 8);
        g2l16(gA + kt + (size_t)64 * K, As + (t + 256) * 8);
        g2l16(gB + kt, Bs + t * 8);
        g2l16(gB + kt + (size_t)64 * K, Bs + (t + 256) * 8);
        __syncthreads();
        bf16x8 af[4], bfr[4];
#pragma unroll
        for (int mi = 0; mi < 4; mi++)
            af[mi] = *(const bf16x8*)(As + (wm * 64 + mi * 16 + l16) * 32 + (quad ^ swz) * 8);
#pragma unroll
        for (int ni = 0; ni < 4; ni++)
            bfr[ni] = *(const bf16x8*)(Bs + (wn * 64 + ni * 16 + l16) * 32 + (quad ^ swz) * 8);
#pragma unroll
        for (int mi = 0; mi < 4; mi++)
#pragma unroll
            for (int ni = 0; ni < 4; ni++)
                acc[mi][ni] = mfma_bf16(af[mi], bfr[ni], acc[mi][ni]);
        __syncthreads();
    }

#pragma unroll
    for (int mi = 0; mi < 4; mi++) {
        int row0 = bm * 128 + wm * 64 + mi * 16 + quad * 4;
#pragma unroll
        for (int ni = 0; ni < 4; ni++) {
            int col = bn * 128 + wn * 64 + ni * 16 + l16;
            float bv = bias[col];
#pragma unroll
            for (int r = 0; r < 4; r++) {
                float v = acc[mi][ni][r] + bv;
                if constexpr (std::is_same<OUT_T, float>::value)
                    C[(size_t)(row0 + r) * N + col] = v;
                else
                    C[(size_t)(row0 + r) * N + col] = __float2bfloat16(v);
            }
        }
    }
}

// ---------------- flash attention (no V staging: PV B-frags from L2/VT) --------
__global__ __launch_bounds__(256, 2) void attn_k(
    const __hip_bfloat16* __restrict__ Qb,
    const __hip_bfloat16* __restrict__ Kb,
    const __hip_bfloat16* __restrict__ VT,
    __hip_bfloat16* __restrict__ AO) {
    constexpr int PLD = 72;
    __shared__ alignas(16) __hip_bfloat16 Ks[64 * 128];
    __shared__ alignas(16) __hip_bfloat16 Ps[4][32 * PLD];

    const int bh = blockIdx.x;          // b*16 + h
    const int b = bh >> 4, h = bh & 15, g = h >> 3;
    const int t = threadIdx.x, lane = t & 63, w = t >> 6;
    const int quad = lane >> 4, l16 = lane & 15;
    const int q0 = blockIdx.y * 128 + w * 32;

    const __hip_bfloat16* Qp = Qb + ((size_t)bh * 1024 + q0 + l16) * 128 + quad * 8;
    bf16x8 aq[2][4];
#pragma unroll
    for (int mi = 0; mi < 2; mi++)
#pragma unroll
        for (int kc = 0; kc < 4; kc++)
            aq[mi][kc] = *(const bf16x8*)(Qp + mi * 16 * 128 + kc * 32);

    const int bg = b * 2 + g;
    const __hip_bfloat16* Kstage = Kb + (size_t)bg * 1024 * 128
        + (t >> 4) * 128 + ((t & 15) ^ (t >> 4)) * 8;
    // PV B-operand read directly from VT (256KB per bg slice, L2-resident,
    // shared by 64 blocks): lane(l16) -> d-row ni*16+l16, k elems kc2*32+quad*8.
    const __hip_bfloat16* Vg = VT + ((size_t)bg * 128 + l16) * 1024 + quad * 8;

    float l_part[2][4] = {};
    floatx4 o[2][8] = {};

    for (int kv = 0; kv < 1024; kv += 64) {
#pragma unroll
        for (int j = 0; j < 4; j++)
            g2l16(Kstage + (size_t)(kv + j * 16) * 128, Ks + (j * 256 + t) * 8);

        // hoist PV B-fragments for this tile: QK^T+softmax covers L2 latency
        bf16x8 vbf[8][2];
#pragma unroll
        for (int ni = 0; ni < 8; ni++)
#pragma unroll
            for (int kc2 = 0; kc2 < 2; kc2++)
                vbf[ni][kc2] = *(const bf16x8*)(Vg + (size_t)ni * 16 * 1024
                                                + kv + kc2 * 32);
        __syncthreads();

        floatx4 s[2][4] = {};
#pragma unroll
        for (int nj = 0; nj < 4; nj++)
#pragma unroll
            for (int kc = 0; kc < 4; kc++) {
                bf16x8 kb = *(const bf16x8*)(Ks + (nj * 16 + l16) * 128
                                             + (((kc * 4 + quad) ^ l16) * 8));
                s[0][nj] = mfma_bf16(aq[0][kc], kb, s[0][nj]);
                s[1][nj] = mfma_bf16(aq[1][kc], kb, s[1][nj]);
            }

        __hip_bfloat16* pl = Ps[w];
#pragma unroll
        for (int mi = 0; mi < 2; mi++)
#pragma unroll
            for (int nj = 0; nj < 4; nj++)
#pragma unroll
                for (int r = 0; r < 4; r++) {
                    float p = __expf(s[mi][nj][r]);
                    l_part[mi][r] += p;
                    pl[(mi * 16 + quad * 4 + r) * PLD + nj * 16 + l16] =
                        __float2bfloat16(p);
                }
        asm volatile("s_waitcnt lgkmcnt(0)" ::: "memory");

        bf16x8 ap[2][2];
#pragma unroll
        for (int mi = 0; mi < 2; mi++)
#pragma unroll
            for (int kc2 = 0; kc2 < 2; kc2++)
                ap[mi][kc2] = *(const bf16x8*)(pl + (mi * 16 + l16) * PLD
                                               + kc2 * 32 + quad * 8);

#pragma unroll
        for (int ni = 0; ni < 8; ni++)
#pragma unroll
            for (int kc2 = 0; kc2 < 2; kc2++) {
                o[0][ni] = mfma_bf16(ap[0][kc2], vbf[ni][kc2], o[0][ni]);
                o[1][ni] = mfma_bf16(ap[1][kc2], vbf[ni][kc2], o[1][ni]);
            }
        __syncthreads();
    }

#pragma unroll
    for (int mi = 0; mi < 2; mi++)
#pragma unroll
        for (int r = 0; r < 4; r++) {
            float sum = l_part[mi][r];
            sum += __shfl_xor(sum, 1);
            sum += __shfl_xor(sum, 2);
            sum += __shfl_xor(sum, 4);
            sum += __shfl_xor(sum, 8);
            float inv = 1.f / sum;
            size_t srow = (size_t)b * 1024 + q0 + mi * 16 + quad * 4 + r;
#pragma unroll
            for (int ni = 0; ni < 8; ni++)
                AO[srow * 2048 + h * 128 + ni * 16 + l16] =
                    __float2bfloat16(o[mi][ni][r] * inv);
        }
}

extern "C" void kernel_launch(void* const* d_in, const int* in_sizes, int n_in,
                              void* d_out, int out_size, void* d_ws, size_t ws_size,
                              hipStream_t stream) {
    (void)in_sizes; (void)n_in; (void)out_size; (void)ws_size;
    const float* x  = (const float*)d_in[0];
    const float* wq = (const float*)d_in[1];
    const float* bq = (const float*)d_in[2];
    const float* wk = (const float*)d_in[3];
    const float* bk = (const float*)d_in[4];
    const float* wv = (const float*)d_in[5];
    const float* bv = (const float*)d_in[6];
    const float* wo = (const float*)d_in[7];
    const float* bo = (const float*)d_in[8];
    float* out = (float*)d_out;

    char* ws = (char*)d_ws;
    __hip_bfloat16* xb    = (__hip_bfloat16*)(ws + 0);          // 16.8 MB (4096x2048)
    __hip_bfloat16* AO    = xb;                                  // alias (xb dead after QKV gemm)
    __hip_bfloat16* wqkvt = (__hip_bfloat16*)(ws + 16777216);   // 10.5 MB (2560x2048)
    __hip_bfloat16* wot   = (__hip_bfloat16*)(ws + 27262976);   // 8.4 MB  (2048x2048)
    __hip_bfloat16* Qb    = (__hip_bfloat16*)(ws + 35651584);   // 16.8 MB (B*H,S,128)
    __hip_bfloat16* Kb    = (__hip_bfloat16*)(ws + 52428800);   // 2.1 MB  (B*G,S,128)
    __hip_bfloat16* VT    = (__hip_bfloat16*)(ws + 56623104);   // 2.1 MB  (B*G,128,S)
    float*          bqkv  = (float*)(ws + 58720256);            // 10 KB   (2560)

    cast_f32_bf16_k<<<8192, 256, 0, stream>>>(x, xb, 2097152);
    prep_k<<<9226, 256, 0, stream>>>(wq, wk, wv, wo, bq, bk, bv, wqkvt, wot, bqkv);
    gemm_qkv_k<<<dim3(20, 32), 256, 0, stream>>>(xb, wqkvt, bqkv, Qb, Kb, VT);
    attn_k<<<dim3(64, 8), 256, 0, stream>>>(Qb, Kb, VT, AO);
    gemm_bt_k<float><<<dim3(16, 32), 256, 0, stream>>>(AO, wot, bo, out, 4096, 2048, 2048);
}

// Round 4
// 298.365 us; speedup vs baseline: 1.0834x; 1.0818x over previous
//
#include <hip/hip_runtime.h>
#include <hip/hip_bf16.h>
#include <type_traits>

// Problem constants: B=4, S=1024, D=2048, H=16, G=2, HD=128
typedef __attribute__((ext_vector_type(8))) __bf16 bf16x8;
typedef __attribute__((ext_vector_type(4))) float floatx4;

__device__ inline floatx4 mfma_bf16(bf16x8 a, bf16x8 b, floatx4 c) {
    return __builtin_amdgcn_mfma_f32_16x16x32_bf16(a, b, c, 0, 0, 0);
}

__device__ inline void g2l16(const __hip_bfloat16* g, __hip_bfloat16* l) {
    __builtin_amdgcn_global_load_lds(
        (const __attribute__((address_space(1))) void*)g,
        (__attribute__((address_space(3))) void*)l, 16, 0, 0);
}

// ---------------- fused: cast f32->bf16 (blocks 0..8191) + weight prep ----------
// bid < 8192: cast x (2097152 float4 groups). bid >= 8192: prep (transpose +
// bias concat), identical to the verified prep_k with bid' = bid - 8192.
__global__ void prep_all_k(const float* __restrict__ x,
                           __hip_bfloat16* __restrict__ xb,
                           const float* __restrict__ wq, const float* __restrict__ wk,
                           const float* __restrict__ wv, const float* __restrict__ wo,
                           const float* __restrict__ bq, const float* __restrict__ bk,
                           const float* __restrict__ bv,
                           __hip_bfloat16* __restrict__ wqkvt,
                           __hip_bfloat16* __restrict__ wot,
                           float* __restrict__ bqkv) {
    int bid0 = blockIdx.x;
    if (bid0 < 8192) {
        int i = bid0 * 256 + threadIdx.x;
        float4 v = ((const float4*)x)[i];
        ushort4 u;
        __hip_bfloat16 a0 = __float2bfloat16(v.x), a1 = __float2bfloat16(v.y);
        __hip_bfloat16 a2 = __float2bfloat16(v.z), a3 = __float2bfloat16(v.w);
        u.x = *(unsigned short*)&a0; u.y = *(unsigned short*)&a1;
        u.z = *(unsigned short*)&a2; u.w = *(unsigned short*)&a3;
        ((ushort4*)xb)[i] = u;
        return;
    }
    int bid = bid0 - 8192;
    if (bid >= 9216) {
        int i = (bid - 9216) * 256 + threadIdx.x;
        if (i < 2560)
            bqkv[i] = (i < 2048) ? bq[i] : (i < 2304 ? bk[i - 2048] : bv[i - 2304]);
        return;
    }
    const float* W; __hip_bfloat16* Wt; int C, row_off, cb, rb;
    if (bid < 4096)      { W = wq; Wt = wqkvt; C = 2048; row_off = 0;
                           cb = bid & 63; rb = bid >> 6; }
    else if (bid < 4608) { W = wk; Wt = wqkvt; C = 256;  row_off = 2048;
                           int id = bid - 4096; cb = id & 7; rb = id >> 3; }
    else if (bid < 5120) { W = wv; Wt = wqkvt; C = 256;  row_off = 2304;
                           int id = bid - 4608; cb = id & 7; rb = id >> 3; }
    else                 { W = wo; Wt = wot;   C = 2048; row_off = 0;
                           int id = bid - 5120; cb = id & 63; rb = id >> 6; }
    __shared__ float tile[32][33];
    int c0 = cb * 32, r0 = rb * 32;
    int tx = threadIdx.x & 31, ty0 = threadIdx.x >> 5;
#pragma unroll
    for (int i = 0; i < 4; i++) {
        int ty = ty0 + i * 8;
        tile[ty][tx] = W[(size_t)(r0 + ty) * C + c0 + tx];
    }
    __syncthreads();
#pragma unroll
    for (int i = 0; i < 4; i++) {
        int ty = ty0 + i * 8;
        Wt[(size_t)(row_off + c0 + ty) * 2048 + r0 + tx] = __float2bfloat16(tile[tx][ty]);
    }
}

// ---------------- fused QKV GEMM + RoPE epilogue (BK=64: half the barriers) ----
// A(4096,2048) @ wqkvt(2560,2048)^T. Round-0 verified fragment layout, staging
// swizzle, and epilogues — the ONLY change: each iteration stages TWO 32-K
// sub-buffers (As[0/1], Bs[0/1], exact round-0 layout each) and runs 32 MFMA
// between one barrier pair instead of 16. LDS 32 KiB.
__global__ __launch_bounds__(256) void gemm_qkv_k(
    const __hip_bfloat16* __restrict__ A,
    const __hip_bfloat16* __restrict__ Bt,
    const float* __restrict__ bias,
    __hip_bfloat16* __restrict__ Qb,
    __hip_bfloat16* __restrict__ Kb,
    __hip_bfloat16* __restrict__ Vlin) {
    __shared__ alignas(16) __hip_bfloat16 As[2][128 * 32];
    __shared__ alignas(16) __hip_bfloat16 Bs[2][128 * 32];
    const int t = threadIdx.x, lane = t & 63, w = t >> 6;
    const int quad = lane >> 4, l16 = lane & 15;
    const int bm = blockIdx.y, bn = blockIdx.x;
    const int r_ = t >> 2;
    const int kc_ = (t & 3) ^ ((t >> 3) & 3);   // swizzled source chunk
    const int swz = (l16 >> 1) & 3;

    const __hip_bfloat16* gA = A + (size_t)(bm * 128 + r_) * 2048 + kc_ * 8;
    const __hip_bfloat16* gB = Bt + (size_t)(bn * 128 + r_) * 2048 + kc_ * 8;

    floatx4 acc[2][8] = {};

    for (int kt = 0; kt < 2048; kt += 64) {
        g2l16(gA + kt,                  As[0] + t * 8);
        g2l16(gA + kt + 64 * 2048,      As[0] + (t + 256) * 8);
        g2l16(gA + kt + 32,             As[1] + t * 8);
        g2l16(gA + kt + 32 + 64 * 2048, As[1] + (t + 256) * 8);
        g2l16(gB + kt,                  Bs[0] + t * 8);
        g2l16(gB + kt + 64 * 2048,      Bs[0] + (t + 256) * 8);
        g2l16(gB + kt + 32,             Bs[1] + t * 8);
        g2l16(gB + kt + 32 + 64 * 2048, Bs[1] + (t + 256) * 8);
        __syncthreads();
#pragma unroll
        for (int s = 0; s < 2; s++) {
            bf16x8 af[2], bfr[8];
#pragma unroll
            for (int mi = 0; mi < 2; mi++)
                af[mi] = *(const bf16x8*)(As[s] + (w * 32 + mi * 16 + l16) * 32
                                          + (quad ^ swz) * 8);
#pragma unroll
            for (int ni = 0; ni < 8; ni++)
                bfr[ni] = *(const bf16x8*)(Bs[s] + (ni * 16 + l16) * 32
                                           + (quad ^ swz) * 8);
#pragma unroll
            for (int mi = 0; mi < 2; mi++)
#pragma unroll
                for (int ni = 0; ni < 8; ni++)
                    acc[mi][ni] = mfma_bf16(af[mi], bfr[ni], acc[mi][ni]);
        }
        __syncthreads();
    }

    const int row_base = bm * 128 + w * 32 + quad * 4;
    if (bn < 18) {
        // Q (bn<16) or K (bn 16/17): RoPE pairs (j, j+64), j = ni*16+l16, ni<4
        const float scale = (bn < 16) ? 0.0078125f : 1.0f;
        __hip_bfloat16* dst = (bn < 16) ? Qb : Kb;
        const int nh = (bn < 16) ? 16 : 2;
        const int hh = (bn < 16) ? bn : (bn - 16);
#pragma unroll
        for (int ni = 0; ni < 4; ni++) {
            int j = ni * 16 + l16;
            float invf = __expf(-(float)j * (9.210340371976184f / 64.f)); // 10000^{-j/64}
            float bj  = bias[bn * 128 + j];
            float bj2 = bias[bn * 128 + j + 64];
#pragma unroll
            for (int mi = 0; mi < 2; mi++)
#pragma unroll
                for (int r = 0; r < 4; r++) {
                    int row = row_base + mi * 16 + r;
                    int b = row >> 10, s = row & 1023;
                    float vj  = acc[mi][ni][r] + bj;
                    float vj2 = acc[mi][ni + 4][r] + bj2;
                    float sn, cs;
                    __sincosf((float)s * invf, &sn, &cs);
                    __hip_bfloat16* op = dst + ((size_t)(b * nh + hh) * 1024 + s) * 128;
                    op[j]      = __float2bfloat16((vj * cs - vj2 * sn) * scale);
                    op[j + 64] = __float2bfloat16((vj2 * cs + vj * sn) * scale);
                }
        }
    } else {
        int g = bn - 18;
#pragma unroll
        for (int ni = 0; ni < 8; ni++) {
            int col = ni * 16 + l16;
            float bv = bias[bn * 128 + col];
#pragma unroll
            for (int mi = 0; mi < 2; mi++)
#pragma unroll
                for (int r = 0; r < 4; r++) {
                    int row = row_base + mi * 16 + r;
                    Vlin[(size_t)row * 256 + g * 128 + col] =
                        __float2bfloat16(acc[mi][ni][r] + bv);
                }
        }
    }
}

// ---------------- GEMM: C(M,N) = A(M,K) @ Bt(N,K)^T + bias (out proj) ----------
// Round-0 structure with BK=64 double sub-buffer (same mechanism as gemm_qkv_k).
template <typename OUT_T>
__global__ __launch_bounds__(256) void gemm_bt_k(
    const __hip_bfloat16* __restrict__ A,
    const __hip_bfloat16* __restrict__ Bt,
    const float* __restrict__ bias,
    OUT_T* __restrict__ C,
    int M, int N, int K) {
    __shared__ alignas(16) __hip_bfloat16 As[2][128 * 32];
    __shared__ alignas(16) __hip_bfloat16 Bs[2][128 * 32];
    const int t = threadIdx.x;
    const int lane = t & 63;
    const int w = t >> 6;
    const int wm = w & 1, wn = w >> 1;
    const int quad = lane >> 4, l16 = lane & 15;
    const int bm = blockIdx.y, bn = blockIdx.x;
    const int r_ = t >> 2;
    const int kc_ = (t & 3) ^ ((t >> 3) & 3);   // swizzled source chunk
    const int swz = (l16 >> 1) & 3;

    const __hip_bfloat16* gA = A + (size_t)(bm * 128 + r_) * K + kc_ * 8;
    const __hip_bfloat16* gB = Bt + (size_t)(bn * 128 + r_) * K + kc_ * 8;

    floatx4 acc[4][4] = {};

    for (int kt = 0; kt < K; kt += 64) {
        g2l16(gA + kt,                        As[0] + t * 8);
        g2l16(gA + kt + (size_t)64 * K,       As[0] + (t + 256) * 8);
        g2l16(gA + kt + 32,                   As[1] + t * 8);
        g2l16(gA + kt + 32 + (size_t)64 * K,  As[1] + (t + 256) * 8);
        g2l16(gB + kt,                        Bs[0] + t * 8);
        g2l16(gB + kt + (size_t)64 * K,       Bs[0] + (t + 256) * 8);
        g2l16(gB + kt + 32,                   Bs[1] + t * 8);
        g2l16(gB + kt + 32 + (size_t)64 * K,  Bs[1] + (t + 256) * 8);
        __syncthreads();
#pragma unroll
        for (int s = 0; s < 2; s++) {
            bf16x8 af[4], bfr[4];
#pragma unroll
            for (int mi = 0; mi < 4; mi++)
                af[mi] = *(const bf16x8*)(As[s] + (wm * 64 + mi * 16 + l16) * 32
                                          + (quad ^ swz) * 8);
#pragma unroll
            for (int ni = 0; ni < 4; ni++)
                bfr[ni] = *(const bf16x8*)(Bs[s] + (wn * 64 + ni * 16 + l16) * 32
                                           + (quad ^ swz) * 8);
#pragma unroll
            for (int mi = 0; mi < 4; mi++)
#pragma unroll
                for (int ni = 0; ni < 4; ni++)
                    acc[mi][ni] = mfma_bf16(af[mi], bfr[ni], acc[mi][ni]);
        }
        __syncthreads();
    }

#pragma unroll
    for (int mi = 0; mi < 4; mi++) {
        int row0 = bm * 128 + wm * 64 + mi * 16 + quad * 4;
#pragma unroll
        for (int ni = 0; ni < 4; ni++) {
            int col = bn * 128 + wn * 64 + ni * 16 + l16;
            float bv = bias[col];
#pragma unroll
            for (int r = 0; r < 4; r++) {
                float v = acc[mi][ni][r] + bv;
                if constexpr (std::is_same<OUT_T, float>::value)
                    C[(size_t)(row0 + r) * N + col] = v;
                else
                    C[(size_t)(row0 + r) * N + col] = __float2bfloat16(v);
            }
        }
    }
}

// V part of Vlin (4096 x 256) -> VT (B, G, 128, 1024)
__global__ void transpose_v_k(const __hip_bfloat16* __restrict__ Vlin,
                              __hip_bfloat16* __restrict__ VT) {
    __shared__ __hip_bfloat16 tile[32][33];
    int bg = blockIdx.z;
    int b = bg >> 1, g = bg & 1;
    int s0 = blockIdx.y * 32, d0 = blockIdx.x * 32;
    int tx = threadIdx.x & 31, ty0 = threadIdx.x >> 5;
#pragma unroll
    for (int i = 0; i < 4; i++) {
        int ty = ty0 + i * 8;
        tile[ty][tx] = Vlin[(size_t)(b * 1024 + s0 + ty) * 256 + g * 128 + d0 + tx];
    }
    __syncthreads();
#pragma unroll
    for (int i = 0; i < 4; i++) {
        int ty = ty0 + i * 8;
        VT[((size_t)(b * 2 + g) * 128 + d0 + ty) * 1024 + s0 + tx] = tile[tx][ty];
    }
}

// ---------------- flash attention (round-0 verified: K and V staged) ----------
__global__ __launch_bounds__(256, 2) void attn_k(
    const __hip_bfloat16* __restrict__ Qb,
    const __hip_bfloat16* __restrict__ Kb,
    const __hip_bfloat16* __restrict__ VT,
    __hip_bfloat16* __restrict__ AO) {
    constexpr int PLD = 72;
    __shared__ alignas(16) __hip_bfloat16 Ks[64 * 128];
    __shared__ alignas(16) __hip_bfloat16 Vs[128 * 64];
    __shared__ alignas(16) __hip_bfloat16 Ps[4][32 * PLD];

    const int bh = blockIdx.x;          // b*16 + h
    const int b = bh >> 4, h = bh & 15, g = h >> 3;
    const int t = threadIdx.x, lane = t & 63, w = t >> 6;
    const int quad = lane >> 4, l16 = lane & 15;
    const int q0 = blockIdx.y * 128 + w * 32;

    const __hip_bfloat16* Qp = Qb + ((size_t)bh * 1024 + q0 + l16) * 128 + quad * 8;
    bf16x8 aq[2][4];
#pragma unroll
    for (int mi = 0; mi < 2; mi++)
#pragma unroll
        for (int kc = 0; kc < 4; kc++)
            aq[mi][kc] = *(const bf16x8*)(Qp + mi * 16 * 128 + kc * 32);

    const int bg = b * 2 + g;
    const __hip_bfloat16* Kstage = Kb + (size_t)bg * 1024 * 128
        + (t >> 4) * 128 + ((t & 15) ^ (t >> 4)) * 8;
    const __hip_bfloat16* Vstage = VT + (size_t)bg * 128 * 1024
        + (t >> 3) * 1024 + ((t & 7) ^ ((t >> 3) & 7)) * 8;

    float l_part[2][4] = {};
    floatx4 o[2][8] = {};

    for (int kv = 0; kv < 1024; kv += 64) {
#pragma unroll
        for (int j = 0; j < 4; j++)
            g2l16(Kstage + (size_t)(kv + j * 16) * 128, Ks + (j * 256 + t) * 8);
#pragma unroll
        for (int j = 0; j < 4; j++)
            g2l16(Vstage + (size_t)j * 32 * 1024 + kv, Vs + (j * 256 + t) * 8);
        __syncthreads();

        floatx4 s[2][4] = {};
#pragma unroll
        for (int nj = 0; nj < 4; nj++)
#pragma unroll
            for (int kc = 0; kc < 4; kc++) {
                bf16x8 kb = *(const bf16x8*)(Ks + (nj * 16 + l16) * 128
                                             + (((kc * 4 + quad) ^ l16) * 8));
                s[0][nj] = mfma_bf16(aq[0][kc], kb, s[0][nj]);
                s[1][nj] = mfma_bf16(aq[1][kc], kb, s[1][nj]);
            }

        __hip_bfloat16* pl = Ps[w];
#pragma unroll
        for (int mi = 0; mi < 2; mi++)
#pragma unroll
            for (int nj = 0; nj < 4; nj++)
#pragma unroll
                for (int r = 0; r < 4; r++) {
                    float p = __expf(s[mi][nj][r]);
                    l_part[mi][r] += p;
                    pl[(mi * 16 + quad * 4 + r) * PLD + nj * 16 + l16] =
                        __float2bfloat16(p);
                }
        asm volatile("s_waitcnt lgkmcnt(0)" ::: "memory");

        bf16x8 ap[2][2];
#pragma unroll
        for (int mi = 0; mi < 2; mi++)
#pragma unroll
            for (int kc2 = 0; kc2 < 2; kc2++)
                ap[mi][kc2] = *(const bf16x8*)(pl + (mi * 16 + l16) * PLD
                                               + kc2 * 32 + quad * 8);

#pragma unroll
        for (int ni = 0; ni < 8; ni++)
#pragma unroll
            for (int kc2 = 0; kc2 < 2; kc2++) {
                bf16x8 vb = *(const bf16x8*)(Vs + (ni * 16 + l16) * 64
                                             + (((kc2 * 4 + quad) ^ (l16 & 7)) * 8));
                o[0][ni] = mfma_bf16(ap[0][kc2], vb, o[0][ni]);
                o[1][ni] = mfma_bf16(ap[1][kc2], vb, o[1][ni]);
            }
        __syncthreads();
    }

#pragma unroll
    for (int mi = 0; mi < 2; mi++)
#pragma unroll
        for (int r = 0; r < 4; r++) {
            float sum = l_part[mi][r];
            sum += __shfl_xor(sum, 1);
            sum += __shfl_xor(sum, 2);
            sum += __shfl_xor(sum, 4);
            sum += __shfl_xor(sum, 8);
            float inv = 1.f / sum;
            size_t srow = (size_t)b * 1024 + q0 + mi * 16 + quad * 4 + r;
#pragma unroll
            for (int ni = 0; ni < 8; ni++)
                AO[srow * 2048 + h * 128 + ni * 16 + l16] =
                    __float2bfloat16(o[mi][ni][r] * inv);
        }
}

extern "C" void kernel_launch(void* const* d_in, const int* in_sizes, int n_in,
                              void* d_out, int out_size, void* d_ws, size_t ws_size,
                              hipStream_t stream) {
    (void)in_sizes; (void)n_in; (void)out_size; (void)ws_size;
    const float* x  = (const float*)d_in[0];
    const float* wq = (const float*)d_in[1];
    const float* bq = (const float*)d_in[2];
    const float* wk = (const float*)d_in[3];
    const float* bk = (const float*)d_in[4];
    const float* wv = (const float*)d_in[5];
    const float* bv = (const float*)d_in[6];
    const float* wo = (const float*)d_in[7];
    const float* bo = (const float*)d_in[8];
    float* out = (float*)d_out;

    char* ws = (char*)d_ws;
    __hip_bfloat16* xb    = (__hip_bfloat16*)(ws + 0);          // 16.8 MB (4096x2048)
    __hip_bfloat16* AO    = xb;                                  // alias (xb dead after QKV gemm)
    __hip_bfloat16* wqkvt = (__hip_bfloat16*)(ws + 16777216);   // 10.5 MB (2560x2048)
    __hip_bfloat16* wot   = (__hip_bfloat16*)(ws + 27262976);   // 8.4 MB  (2048x2048)
    __hip_bfloat16* Qb    = (__hip_bfloat16*)(ws + 35651584);   // 16.8 MB (B*H,S,128)
    __hip_bfloat16* Kb    = (__hip_bfloat16*)(ws + 52428800);   // 2.1 MB  (B*G,S,128)
    __hip_bfloat16* Vlin  = (__hip_bfloat16*)(ws + 54525952);   // 2.1 MB  (4096x256)
    __hip_bfloat16* VT    = (__hip_bfloat16*)(ws + 56623104);   // 2.1 MB  (B*G,128,S)
    float*          bqkv  = (float*)(ws + 58720256);            // 10 KB   (2560)

    prep_all_k<<<17418, 256, 0, stream>>>(x, xb, wq, wk, wv, wo, bq, bk, bv,
                                          wqkvt, wot, bqkv);
    gemm_qkv_k<<<dim3(20, 32), 256, 0, stream>>>(xb, wqkvt, bqkv, Qb, Kb, Vlin);
    transpose_v_k<<<dim3(4, 32, 8), 256, 0, stream>>>(Vlin, VT);
    attn_k<<<dim3(64, 8), 256, 0, stream>>>(Qb, Kb, VT, AO);
    gemm_bt_k<float><<<dim3(16, 32), 256, 0, stream>>>(AO, wot, bo, out, 4096, 2048, 2048);
}

// Round 5
// 287.309 us; speedup vs baseline: 1.1251x; 1.0385x over previous
//
#include <hip/hip_runtime.h>
#include <hip/hip_bf16.h>
#include <type_traits>

// Problem constants: B=4, S=1024, D=2048, H=16, G=2, HD=128
typedef __attribute__((ext_vector_type(8))) __bf16 bf16x8;
typedef __attribute__((ext_vector_type(4))) float floatx4;

__device__ inline floatx4 mfma_bf16(bf16x8 a, bf16x8 b, floatx4 c) {
    return __builtin_amdgcn_mfma_f32_16x16x32_bf16(a, b, c, 0, 0, 0);
}

__device__ inline void g2l16(const __hip_bfloat16* g, __hip_bfloat16* l) {
    __builtin_amdgcn_global_load_lds(
        (const __attribute__((address_space(1))) void*)g,
        (__attribute__((address_space(3))) void*)l, 16, 0, 0);
}

// ---------------- fused: cast f32->bf16 (blocks 0..8191) + weight prep ----------
__global__ void prep_all_k(const float* __restrict__ x,
                           __hip_bfloat16* __restrict__ xb,
                           const float* __restrict__ wq, const float* __restrict__ wk,
                           const float* __restrict__ wv, const float* __restrict__ wo,
                           const float* __restrict__ bq, const float* __restrict__ bk,
                           const float* __restrict__ bv,
                           __hip_bfloat16* __restrict__ wqkvt,
                           __hip_bfloat16* __restrict__ wot,
                           float* __restrict__ bqkv) {
    int bid0 = blockIdx.x;
    if (bid0 < 8192) {
        int i = bid0 * 256 + threadIdx.x;
        float4 v = ((const float4*)x)[i];
        ushort4 u;
        __hip_bfloat16 a0 = __float2bfloat16(v.x), a1 = __float2bfloat16(v.y);
        __hip_bfloat16 a2 = __float2bfloat16(v.z), a3 = __float2bfloat16(v.w);
        u.x = *(unsigned short*)&a0; u.y = *(unsigned short*)&a1;
        u.z = *(unsigned short*)&a2; u.w = *(unsigned short*)&a3;
        ((ushort4*)xb)[i] = u;
        return;
    }
    int bid = bid0 - 8192;
    if (bid >= 9216) {
        int i = (bid - 9216) * 256 + threadIdx.x;
        if (i < 2560)
            bqkv[i] = (i < 2048) ? bq[i] : (i < 2304 ? bk[i - 2048] : bv[i - 2304]);
        return;
    }
    const float* W; __hip_bfloat16* Wt; int C, row_off, cb, rb;
    if (bid < 4096)      { W = wq; Wt = wqkvt; C = 2048; row_off = 0;
                           cb = bid & 63; rb = bid >> 6; }
    else if (bid < 4608) { W = wk; Wt = wqkvt; C = 256;  row_off = 2048;
                           int id = bid - 4096; cb = id & 7; rb = id >> 3; }
    else if (bid < 5120) { W = wv; Wt = wqkvt; C = 256;  row_off = 2304;
                           int id = bid - 4608; cb = id & 7; rb = id >> 3; }
    else                 { W = wo; Wt = wot;   C = 2048; row_off = 0;
                           int id = bid - 5120; cb = id & 63; rb = id >> 6; }
    __shared__ float tile[32][33];
    int c0 = cb * 32, r0 = rb * 32;
    int tx = threadIdx.x & 31, ty0 = threadIdx.x >> 5;
#pragma unroll
    for (int i = 0; i < 4; i++) {
        int ty = ty0 + i * 8;
        tile[ty][tx] = W[(size_t)(r0 + ty) * C + c0 + tx];
    }
    __syncthreads();
#pragma unroll
    for (int i = 0; i < 4; i++) {
        int ty = ty0 + i * 8;
        Wt[(size_t)(row_off + c0 + ty) * 2048 + r0 + tx] = __float2bfloat16(tile[tx][ty]);
    }
}

// ---------------- fused QKV GEMM + RoPE epilogue (round-0 verified, FROZEN) ----
__global__ __launch_bounds__(256) void gemm_qkv_k(
    const __hip_bfloat16* __restrict__ A,
    const __hip_bfloat16* __restrict__ Bt,
    const float* __restrict__ bias,
    __hip_bfloat16* __restrict__ Qb,
    __hip_bfloat16* __restrict__ Kb,
    __hip_bfloat16* __restrict__ Vlin) {
    __shared__ alignas(16) __hip_bfloat16 As[128 * 32];
    __shared__ alignas(16) __hip_bfloat16 Bs[128 * 32];
    const int t = threadIdx.x, lane = t & 63, w = t >> 6;
    const int quad = lane >> 4, l16 = lane & 15;
    const int bm = blockIdx.y, bn = blockIdx.x;
    const int r_ = t >> 2;
    const int kc_ = (t & 3) ^ ((t >> 3) & 3);   // swizzled source chunk
    const int swz = (l16 >> 1) & 3;

    const __hip_bfloat16* gA = A + (size_t)(bm * 128 + r_) * 2048 + kc_ * 8;
    const __hip_bfloat16* gB = Bt + (size_t)(bn * 128 + r_) * 2048 + kc_ * 8;

    floatx4 acc[2][8] = {};

    for (int kt = 0; kt < 2048; kt += 32) {
        g2l16(gA + kt, As + t * 8);
        g2l16(gA + kt + 64 * 2048, As + (t + 256) * 8);
        g2l16(gB + kt, Bs + t * 8);
        g2l16(gB + kt + 64 * 2048, Bs + (t + 256) * 8);
        __syncthreads();
        bf16x8 af[2], bfr[8];
#pragma unroll
        for (int mi = 0; mi < 2; mi++)
            af[mi] = *(const bf16x8*)(As + (w * 32 + mi * 16 + l16) * 32 + (quad ^ swz) * 8);
#pragma unroll
        for (int ni = 0; ni < 8; ni++)
            bfr[ni] = *(const bf16x8*)(Bs + (ni * 16 + l16) * 32 + (quad ^ swz) * 8);
#pragma unroll
        for (int mi = 0; mi < 2; mi++)
#pragma unroll
            for (int ni = 0; ni < 8; ni++)
                acc[mi][ni] = mfma_bf16(af[mi], bfr[ni], acc[mi][ni]);
        __syncthreads();
    }

    const int row_base = bm * 128 + w * 32 + quad * 4;
    if (bn < 18) {
        // Q (bn<16) or K (bn 16/17): RoPE pairs (j, j+64), j = ni*16+l16, ni<4
        const float scale = (bn < 16) ? 0.0078125f : 1.0f;
        __hip_bfloat16* dst = (bn < 16) ? Qb : Kb;
        const int nh = (bn < 16) ? 16 : 2;
        const int hh = (bn < 16) ? bn : (bn - 16);
#pragma unroll
        for (int ni = 0; ni < 4; ni++) {
            int j = ni * 16 + l16;
            float invf = __expf(-(float)j * (9.210340371976184f / 64.f)); // 10000^{-j/64}
            float bj  = bias[bn * 128 + j];
            float bj2 = bias[bn * 128 + j + 64];
#pragma unroll
            for (int mi = 0; mi < 2; mi++)
#pragma unroll
                for (int r = 0; r < 4; r++) {
                    int row = row_base + mi * 16 + r;
                    int b = row >> 10, s = row & 1023;
                    float vj  = acc[mi][ni][r] + bj;
                    float vj2 = acc[mi][ni + 4][r] + bj2;
                    float sn, cs;
                    __sincosf((float)s * invf, &sn, &cs);
                    __hip_bfloat16* op = dst + ((size_t)(b * nh + hh) * 1024 + s) * 128;
                    op[j]      = __float2bfloat16((vj * cs - vj2 * sn) * scale);
                    op[j + 64] = __float2bfloat16((vj2 * cs + vj * sn) * scale);
                }
        }
    } else {
        int g = bn - 18;
#pragma unroll
        for (int ni = 0; ni < 8; ni++) {
            int col = ni * 16 + l16;
            float bv = bias[bn * 128 + col];
#pragma unroll
            for (int mi = 0; mi < 2; mi++)
#pragma unroll
                for (int r = 0; r < 4; r++) {
                    int row = row_base + mi * 16 + r;
                    Vlin[(size_t)row * 256 + g * 128 + col] =
                        __float2bfloat16(acc[mi][ni][r] + bv);
                }
        }
    }
}

// ---------------- GEMM: C(M,N) = A(M,K) @ Bt(N,K)^T + bias (round-0, FROZEN) ---
template <typename OUT_T>
__global__ __launch_bounds__(256) void gemm_bt_k(
    const __hip_bfloat16* __restrict__ A,
    const __hip_bfloat16* __restrict__ Bt,
    const float* __restrict__ bias,
    OUT_T* __restrict__ C,
    int M, int N, int K) {
    __shared__ alignas(16) __hip_bfloat16 As[128 * 32];
    __shared__ alignas(16) __hip_bfloat16 Bs[128 * 32];
    const int t = threadIdx.x;
    const int lane = t & 63;
    const int w = t >> 6;
    const int wm = w & 1, wn = w >> 1;
    const int quad = lane >> 4, l16 = lane & 15;
    const int bm = blockIdx.y, bn = blockIdx.x;
    const int r_ = t >> 2;
    const int kc_ = (t & 3) ^ ((t >> 3) & 3);   // swizzled source chunk
    const int swz = (l16 >> 1) & 3;

    const __hip_bfloat16* gA = A + (size_t)(bm * 128 + r_) * K + kc_ * 8;
    const __hip_bfloat16* gB = Bt + (size_t)(bn * 128 + r_) * K + kc_ * 8;

    floatx4 acc[4][4] = {};

    for (int kt = 0; kt < K; kt += 32) {
        g2l16(gA + kt, As + t * 8);
        g2l16(gA + kt + (size_t)64 * K, As + (t + 256) * 8);
        g2l16(gB + kt, Bs + t * 8);
        g2l16(gB + kt + (size_t)64 * K, Bs + (t + 256) * 8);
        __syncthreads();
        bf16x8 af[4], bfr[4];
#pragma unroll
        for (int mi = 0; mi < 4; mi++)
            af[mi] = *(const bf16x8*)(As + (wm * 64 + mi * 16 + l16) * 32 + (quad ^ swz) * 8);
#pragma unroll
        for (int ni = 0; ni < 4; ni++)
            bfr[ni] = *(const bf16x8*)(Bs + (wn * 64 + ni * 16 + l16) * 32 + (quad ^ swz) * 8);
#pragma unroll
        for (int mi = 0; mi < 4; mi++)
#pragma unroll
            for (int ni = 0; ni < 4; ni++)
                acc[mi][ni] = mfma_bf16(af[mi], bfr[ni], acc[mi][ni]);
        __syncthreads();
    }

#pragma unroll
    for (int mi = 0; mi < 4; mi++) {
        int row0 = bm * 128 + wm * 64 + mi * 16 + quad * 4;
#pragma unroll
        for (int ni = 0; ni < 4; ni++) {
            int col = bn * 128 + wn * 64 + ni * 16 + l16;
            float bv = bias[col];
#pragma unroll
            for (int r = 0; r < 4; r++) {
                float v = acc[mi][ni][r] + bv;
                if constexpr (std::is_same<OUT_T, float>::value)
                    C[(size_t)(row0 + r) * N + col] = v;
                else
                    C[(size_t)(row0 + r) * N + col] = __float2bfloat16(v);
            }
        }
    }
}

// V part of Vlin (4096 x 256) -> VT (B, G, 128, 1024)
__global__ void transpose_v_k(const __hip_bfloat16* __restrict__ Vlin,
                              __hip_bfloat16* __restrict__ VT) {
    __shared__ __hip_bfloat16 tile[32][33];
    int bg = blockIdx.z;
    int b = bg >> 1, g = bg & 1;
    int s0 = blockIdx.y * 32, d0 = blockIdx.x * 32;
    int tx = threadIdx.x & 31, ty0 = threadIdx.x >> 5;
#pragma unroll
    for (int i = 0; i < 4; i++) {
        int ty = ty0 + i * 8;
        tile[ty][tx] = Vlin[(size_t)(b * 1024 + s0 + ty) * 256 + g * 128 + d0 + tx];
    }
    __syncthreads();
#pragma unroll
    for (int i = 0; i < 4; i++) {
        int ty = ty0 + i * 8;
        VT[((size_t)(b * 2 + g) * 128 + d0 + ty) * 1024 + s0 + tx] = tile[tx][ty];
    }
}

// ---------------- flash attention: 16 q-rows/wave, grid (64,16) = 4 blk/CU -----
// Same verified per-tile structure as round 0 (K+V staged with XOR swizzle,
// P via per-wave LDS), with the mi-dimension removed: each wave owns 16 q-rows.
// LDS 41 KB -> 3 resident blocks/CU (12 waves) vs round-0's 2 blocks (8 waves).
__global__ __launch_bounds__(256, 3) void attn_k(
    const __hip_bfloat16* __restrict__ Qb,
    const __hip_bfloat16* __restrict__ Kb,
    const __hip_bfloat16* __restrict__ VT,
    __hip_bfloat16* __restrict__ AO) {
    constexpr int PLD = 72;
    __shared__ alignas(16) __hip_bfloat16 Ks[64 * 128];
    __shared__ alignas(16) __hip_bfloat16 Vs[128 * 64];
    __shared__ alignas(16) __hip_bfloat16 Ps[4][16 * PLD];

    const int bh = blockIdx.x;          // b*16 + h
    const int b = bh >> 4, h = bh & 15, g = h >> 3;
    const int t = threadIdx.x, lane = t & 63, w = t >> 6;
    const int quad = lane >> 4, l16 = lane & 15;
    const int q0 = blockIdx.y * 64 + w * 16;

    const __hip_bfloat16* Qp = Qb + ((size_t)bh * 1024 + q0 + l16) * 128 + quad * 8;
    bf16x8 aq[4];
#pragma unroll
    for (int kc = 0; kc < 4; kc++)
        aq[kc] = *(const bf16x8*)(Qp + kc * 32);

    const int bg = b * 2 + g;
    const __hip_bfloat16* Kstage = Kb + (size_t)bg * 1024 * 128
        + (t >> 4) * 128 + ((t & 15) ^ (t >> 4)) * 8;
    const __hip_bfloat16* Vstage = VT + (size_t)bg * 128 * 1024
        + (t >> 3) * 1024 + ((t & 7) ^ ((t >> 3) & 7)) * 8;

    float l_part[4] = {};
    floatx4 o[8] = {};

    for (int kv = 0; kv < 1024; kv += 64) {
#pragma unroll
        for (int j = 0; j < 4; j++)
            g2l16(Kstage + (size_t)(kv + j * 16) * 128, Ks + (j * 256 + t) * 8);
#pragma unroll
        for (int j = 0; j < 4; j++)
            g2l16(Vstage + (size_t)j * 32 * 1024 + kv, Vs + (j * 256 + t) * 8);
        __syncthreads();

        floatx4 s[4] = {};
#pragma unroll
        for (int nj = 0; nj < 4; nj++)
#pragma unroll
            for (int kc = 0; kc < 4; kc++) {
                bf16x8 kb = *(const bf16x8*)(Ks + (nj * 16 + l16) * 128
                                             + (((kc * 4 + quad) ^ l16) * 8));
                s[nj] = mfma_bf16(aq[kc], kb, s[nj]);
            }

        __hip_bfloat16* pl = Ps[w];
#pragma unroll
        for (int nj = 0; nj < 4; nj++)
#pragma unroll
            for (int r = 0; r < 4; r++) {
                float p = __expf(s[nj][r]);
                l_part[r] += p;
                pl[(quad * 4 + r) * PLD + nj * 16 + l16] = __float2bfloat16(p);
            }
        asm volatile("s_waitcnt lgkmcnt(0)" ::: "memory");

        bf16x8 ap[2];
#pragma unroll
        for (int kc2 = 0; kc2 < 2; kc2++)
            ap[kc2] = *(const bf16x8*)(pl + l16 * PLD + kc2 * 32 + quad * 8);

#pragma unroll
        for (int ni = 0; ni < 8; ni++)
#pragma unroll
            for (int kc2 = 0; kc2 < 2; kc2++) {
                bf16x8 vb = *(const bf16x8*)(Vs + (ni * 16 + l16) * 64
                                             + (((kc2 * 4 + quad) ^ (l16 & 7)) * 8));
                o[ni] = mfma_bf16(ap[kc2], vb, o[ni]);
            }
        __syncthreads();
    }

#pragma unroll
    for (int r = 0; r < 4; r++) {
        float sum = l_part[r];
        sum += __shfl_xor(sum, 1);
        sum += __shfl_xor(sum, 2);
        sum += __shfl_xor(sum, 4);
        sum += __shfl_xor(sum, 8);
        float inv = 1.f / sum;
        size_t srow = (size_t)b * 1024 + q0 + quad * 4 + r;
#pragma unroll
        for (int ni = 0; ni < 8; ni++)
            AO[srow * 2048 + h * 128 + ni * 16 + l16] =
                __float2bfloat16(o[ni][r] * inv);
    }
}

extern "C" void kernel_launch(void* const* d_in, const int* in_sizes, int n_in,
                              void* d_out, int out_size, void* d_ws, size_t ws_size,
                              hipStream_t stream) {
    (void)in_sizes; (void)n_in; (void)out_size; (void)ws_size;
    const float* x  = (const float*)d_in[0];
    const float* wq = (const float*)d_in[1];
    const float* bq = (const float*)d_in[2];
    const float* wk = (const float*)d_in[3];
    const float* bk = (const float*)d_in[4];
    const float* wv = (const float*)d_in[5];
    const float* bv = (const float*)d_in[6];
    const float* wo = (const float*)d_in[7];
    const float* bo = (const float*)d_in[8];
    float* out = (float*)d_out;

    char* ws = (char*)d_ws;
    __hip_bfloat16* xb    = (__hip_bfloat16*)(ws + 0);          // 16.8 MB (4096x2048)
    __hip_bfloat16* AO    = xb;                                  // alias (xb dead after QKV gemm)
    __hip_bfloat16* wqkvt = (__hip_bfloat16*)(ws + 16777216);   // 10.5 MB (2560x2048)
    __hip_bfloat16* wot   = (__hip_bfloat16*)(ws + 27262976);   // 8.4 MB  (2048x2048)
    __hip_bfloat16* Qb    = (__hip_bfloat16*)(ws + 35651584);   // 16.8 MB (B*H,S,128)
    __hip_bfloat16* Kb    = (__hip_bfloat16*)(ws + 52428800);   // 2.1 MB  (B*G,S,128)
    __hip_bfloat16* Vlin  = (__hip_bfloat16*)(ws + 54525952);   // 2.1 MB  (4096x256)
    __hip_bfloat16* VT    = (__hip_bfloat16*)(ws + 56623104);   // 2.1 MB  (B*G,128,S)
    float*          bqkv  = (float*)(ws + 58720256);            // 10 KB   (2560)

    prep_all_k<<<17418, 256, 0, stream>>>(x, xb, wq, wk, wv, wo, bq, bk, bv,
                                          wqkvt, wot, bqkv);
    gemm_qkv_k<<<dim3(20, 32), 256, 0, stream>>>(xb, wqkvt, bqkv, Qb, Kb, Vlin);
    transpose_v_k<<<dim3(4, 32, 8), 256, 0, stream>>>(Vlin, VT);
    attn_k<<<dim3(64, 16), 256, 0, stream>>>(Qb, Kb, VT, AO);
    gemm_bt_k<float><<<dim3(16, 32), 256, 0, stream>>>(AO, wot, bo, out, 4096, 2048, 2048);
}